// Round 1
// 1656.855 us; speedup vs baseline: 1.1920x; 1.1920x over previous
//
#include <hip/hip_runtime.h>
#include <hip/hip_bf16.h>

// ---------------------------------------------------------------------------
// Types
// ---------------------------------------------------------------------------
typedef __bf16 bf16;
typedef __bf16 bf16x8 __attribute__((ext_vector_type(8)));
typedef float  f32x4  __attribute__((ext_vector_type(4)));

// async global->LDS, 16B per lane; LDS dest = wave-uniform base + lane*16
__device__ __forceinline__ void gl2lds16(const bf16* g, bf16* l) {
    __builtin_amdgcn_global_load_lds((const __attribute__((address_space(1))) void*)g,
                                     (__attribute__((address_space(3))) void*)l,
                                     16, 0, 0);
}

// ---------------------------------------------------------------------------
// relu + cast: fp32 in, bf16 out. 8 elems / thread.
// ---------------------------------------------------------------------------
__global__ void relu_cast_kernel(const float* __restrict__ x, bf16* __restrict__ y, int n8) {
    int i = blockIdx.x * 256 + threadIdx.x;
    if (i >= n8) return;
    const float4* xp = (const float4*)x + (size_t)i * 2;
    float4 a = xp[0], b = xp[1];
    bf16x8 o;
    o[0] = (bf16)fmaxf(a.x, 0.f); o[1] = (bf16)fmaxf(a.y, 0.f);
    o[2] = (bf16)fmaxf(a.z, 0.f); o[3] = (bf16)fmaxf(a.w, 0.f);
    o[4] = (bf16)fmaxf(b.x, 0.f); o[5] = (bf16)fmaxf(b.y, 0.f);
    o[6] = (bf16)fmaxf(b.z, 0.f); o[7] = (bf16)fmaxf(b.w, 0.f);
    *(bf16x8*)(y + (size_t)i * 8) = o;
}

// ---------------------------------------------------------------------------
// Masked mean: mean[b,n] = sum_s mask[b,s]*x[b,s,n] / sum_s mask[b,s]
// grid = (4, B), block = 256; each thread owns one column n.
// ---------------------------------------------------------------------------
__global__ void mean_kernel(const float* __restrict__ x, const float* __restrict__ mask,
                            float* __restrict__ mean, int S) {
    int b = blockIdx.y;
    int n = blockIdx.x * 256 + threadIdx.x;
    const float* xb = x + (size_t)b * S * 1024;
    const float* mb = mask + (size_t)b * S;
    float acc = 0.f, msum = 0.f;
    for (int s = 0; s < S; ++s) {
        float mk = mb[s];
        msum += mk;
        acc += mk * xb[(size_t)s * 1024 + n];
    }
    mean[b * 1024 + n] = acc / msum;
}

// ---------------------------------------------------------------------------
// gate[b,n] = sigmoid( relu(mean[b,:]) @ W[:,n] + bias[n] );  W fp32 [1024,1024]
// grid = (4, B), block = 256
// ---------------------------------------------------------------------------
__global__ void gate_kernel(const float* __restrict__ mean, const float* __restrict__ W,
                            const float* __restrict__ bias, float* __restrict__ gate) {
    int b = blockIdx.y;
    int n = blockIdx.x * 256 + threadIdx.x;
    const float* mb = mean + b * 1024;
    float acc = 0.f;
    for (int k = 0; k < 1024; ++k) {
        float a = mb[k];
        a = a > 0.f ? a : 0.f;
        acc += a * W[(size_t)k * 1024 + n];
    }
    acc += bias[n];
    gate[b * 1024 + n] = 1.0f / (1.0f + __expf(-acc));
}

// ---------------------------------------------------------------------------
// Wt[n,k] = (bf16)W[k,n]; fp32 in, bf16 out. block=(32,8), grid=(K/32, N/32)
// ---------------------------------------------------------------------------
__global__ void transpose_kernel(const float* __restrict__ W, bf16* __restrict__ Wt,
                                 int K, int N) {
    __shared__ bf16 tile[32][33];
    int k0 = blockIdx.x * 32, n0 = blockIdx.y * 32;
    int tx = threadIdx.x, ty = threadIdx.y;
#pragma unroll
    for (int i = 0; i < 4; ++i)
        tile[ty * 4 + i][tx] = (bf16)W[(size_t)(k0 + ty * 4 + i) * N + n0 + tx];
    __syncthreads();
#pragma unroll
    for (int i = 0; i < 4; ++i)
        Wt[(size_t)(n0 + ty * 4 + i) * K + k0 + tx] = tile[tx][ty * 4 + i];
}

// ---------------------------------------------------------------------------
// C[M,N] = A[M,1024] @ Bt[N,1024]^T  (+bias fp32, optional *mask[m], *(1+gate))
// 128x128 block, BK=32, 4 waves (2x2), 4x4 16x16x32 MFMA tiles/wave.
// grid = (N/128, M/128), block = 256. OutT = bf16 (trans) or float (d_out).
// ---------------------------------------------------------------------------
template <typename OutT>
__global__ void gemm_bt(const bf16* __restrict__ A, const bf16* __restrict__ Bt,
                        const float* __restrict__ bias, OutT* __restrict__ C,
                        int M, int N,
                        const float* __restrict__ mask,   // [M] or null
                        const float* __restrict__ gate,   // [B,1024] or null
                        int s_shift)                      // batch = m >> s_shift
{
    const int K = 1024;
    __shared__ __align__(16) bf16 Al[128 * 32];
    __shared__ __align__(16) bf16 Bl[128 * 32];

    int tid  = threadIdx.x;
    int lane = tid & 63, w = tid >> 6;
    int wm = w >> 1, wn = w & 1;
    int quad = lane >> 4, l16 = lane & 15;
    int bm = blockIdx.y, bn = blockIdx.x;

    const bf16* Ab = A  + (size_t)bm * 128 * K;
    const bf16* Bb = Bt + (size_t)bn * 128 * K;

    f32x4 acc[4][4];
    f32x4 zero = {0.f, 0.f, 0.f, 0.f};
#pragma unroll
    for (int i = 0; i < 4; ++i)
#pragma unroll
        for (int j = 0; j < 4; ++j) acc[i][j] = zero;

    for (int k0 = 0; k0 < K; k0 += 32) {
        __syncthreads();
#pragma unroll
        for (int p = 0; p < 2; ++p) {
            int c   = p * 256 + tid;
            int row = c >> 2, c8 = (c & 3) * 8;
            bf16* ldsb_a = Al + (size_t)(p * 256 + w * 64) * 8;
            bf16* ldsb_b = Bl + (size_t)(p * 256 + w * 64) * 8;
            gl2lds16(Ab + (size_t)row * K + k0 + c8, ldsb_a);
            gl2lds16(Bb + (size_t)row * K + k0 + c8, ldsb_b);
        }
        __syncthreads();

        bf16x8 af[4], bfr[4];
#pragma unroll
        for (int mt = 0; mt < 4; ++mt)
            af[mt] = *(const bf16x8*)&Al[(wm * 64 + mt * 16 + l16) * 32 + quad * 8];
#pragma unroll
        for (int nt = 0; nt < 4; ++nt)
            bfr[nt] = *(const bf16x8*)&Bl[(wn * 64 + nt * 16 + l16) * 32 + quad * 8];
#pragma unroll
        for (int mt = 0; mt < 4; ++mt)
#pragma unroll
            for (int nt = 0; nt < 4; ++nt)
                acc[mt][nt] = __builtin_amdgcn_mfma_f32_16x16x32_bf16(
                    af[mt], bfr[nt], acc[mt][nt], 0, 0, 0);
    }

    // epilogue: C/D layout col = lane&15, row = quad*4 + reg
#pragma unroll
    for (int mt = 0; mt < 4; ++mt) {
#pragma unroll
        for (int nt = 0; nt < 4; ++nt) {
#pragma unroll
            for (int r = 0; r < 4; ++r) {
                int mrow = bm * 128 + wm * 64 + mt * 16 + quad * 4 + r;
                int ncol = bn * 128 + wn * 64 + nt * 16 + l16;
                float v = acc[mt][nt][r] + bias[ncol];
                if (mask) {
                    v *= mask[mrow];
                    if (gate && ncol < 2048) {
                        int b = mrow >> s_shift;
                        v *= 1.0f + gate[b * 1024 + (ncol & 1023)];
                    }
                }
                C[(size_t)mrow * N + ncol] = (OutT)v;
            }
        }
    }
}

// ---------------------------------------------------------------------------
// Fused flash attention over one (b, h, 64-row Q tile).
// trans: bf16 [B*S, 3072] = [K | Q | V] thirds (already masked + gated).
// Memory token (t=0 when has_mem): K row = 32*mvk*(1+gate), V row = mvv (fp32 srcs).
// Scores: s = (mask ? q.k : -1e9) / sqrt(128); online softmax; O += P@V.
// Epilogue writes upd = X(fp32) + O/l as bf16 (residual fused).
// block = 256 (4 waves; wave w owns S rows [16w,16w+16)).
//
// v2 changes (bank-conflict + occupancy round):
//  - Q held in registers (4x bf16x8/lane, loaded once from global): Ql LDS
//    array, its staging and its conflicted reads removed. LDS 60416->44032 B
//    => 3 blocks/CU (was 2).
//  - Kl chunk-XOR swizzle (ct ^= row&7), involution applied on the PRE-SWIZZLED
//    GLOBAL SOURCE of gl2lds (LDS dest stays linear, rule #21) and on the MFMA
//    read => ds_read_b128 balanced 8 lanes/bank-group (was 16/group).
//  - Vt transpose-write swizzle keyed on (d>>3)&7 at 16B chunk granularity:
//    write banks 16-way -> 2-way; reads stay balanced (row term 4*(l16&7)).
// ---------------------------------------------------------------------------
__global__ __launch_bounds__(256)
void attn_kernel(const bf16* __restrict__ trans, const float* __restrict__ X,
                 bf16* __restrict__ upd, const float* __restrict__ mask,
                 const float* __restrict__ gate,   // null => no mem-token gating
                 const float* __restrict__ mvk, const float* __restrict__ mvv,
                 int S, int T0, int has_mem)
{
    const int T = T0 + has_mem;
    const size_t rs = 3072;
    __shared__ __align__(16) bf16 Kl[64 * 128];
    __shared__ __align__(16) bf16 Vt[128 * 72];   // [d][t], stride 72, chunk-swizzled
    __shared__ __align__(16) bf16 Pl[4 * 16 * 72];

    int tid  = threadIdx.x;
    int lane = tid & 63, w = tid >> 6;
    int quad = lane >> 4, l16 = lane & 15;
    int st = blockIdx.x, h = blockIdx.y, b = blockIdx.z;
    int s0 = st * 64;
    const bf16* Tb = trans + (size_t)b * S * rs;   // S == T0 for all modalities

    // Q fragments in registers: A[m=l16][k=kc+quad*8..+8] for this wave's rows.
    bf16x8 qf[4];
    {
        const bf16* qp = Tb + (size_t)(s0 + w * 16 + l16) * rs + 1024 + h * 128 + quad * 8;
#pragma unroll
        for (int kk = 0; kk < 4; ++kk)
            qf[kk] = *(const bf16x8*)(qp + kk * 32);
    }

    float m_st[4], l_st[4];
    f32x4 o_acc[8];
    f32x4 zero = {0.f, 0.f, 0.f, 0.f};
#pragma unroll
    for (int r = 0; r < 4; ++r) { m_st[r] = -3.0e38f; l_st[r] = 0.f; }
#pragma unroll
    for (int n = 0; n < 8; ++n) o_acc[n] = zero;

    const float inv_sqrt = 0.08838834764831845f;   // 1/sqrt(128)
    int nT = (T + 63) >> 6;
    for (int kt = 0; kt < nT; ++kt) {
        int t0 = kt * 64;
        __syncthreads();   // previous tile's LDS fully consumed

        // stage K tile (64 x 128), k-third at col 0; clamp OOB rows (masked later).
        // LDS dest linear; global source chunk pre-swizzled: ct_g = ct ^ (row&7).
#pragma unroll
        for (int p = 0; p < 4; ++p) {
            int c = p * 256 + tid;
            int row = c >> 4;
            int c16 = ((c & 15) ^ (row & 7)) * 8;
            int t = t0 + row;
            int sr = has_mem ? (t - 1) : t;
            sr = sr < 0 ? 0 : sr;
            sr = sr > T0 - 1 ? T0 - 1 : sr;
            gl2lds16(Tb + (size_t)sr * rs + h * 128 + c16,
                     Kl + (size_t)(p * 256 + w * 64) * 8);
        }
        // stage V tile transposed into Vt[d][t], t-chunk swizzled by (d>>3)&7
#pragma unroll
        for (int i = 0; i < 4; ++i) {
            int chunk = i * 256 + tid;
            int tl = chunk >> 4;
            int d8 = (chunk & 15) * 8;
            int t = t0 + tl;
            bf16 vbuf[8];
            if (has_mem && t == 0) {
                const float* mp = mvv + h * 128 + d8;      // mem V (scale 1), fp32
#pragma unroll
                for (int j = 0; j < 8; ++j) vbuf[j] = (bf16)mp[j];
            } else {
                int sr = has_mem ? (t - 1) : t;
                sr = sr < 0 ? 0 : sr;
                sr = sr > T0 - 1 ? T0 - 1 : sr;
                bf16x8 vv = *(const bf16x8*)(Tb + (size_t)sr * rs + 2048 + h * 128 + d8);
#pragma unroll
                for (int j = 0; j < 8; ++j) vbuf[j] = vv[j];
            }
            // (d8+j)>>3 == d8>>3 for j<8, so the swizzle term is hoisted
            int tswz = (((tl >> 3) ^ ((d8 >> 3) & 7)) << 3) + (tl & 7);
#pragma unroll
            for (int j = 0; j < 8; ++j)
                Vt[(d8 + j) * 72 + tswz] = vbuf[j];
        }
        __syncthreads();   // drains vmcnt (global_load_lds) + lgkm (ds writes)

        // overwrite mem-token K row: 32 * mvk * (1+gate); row 0 => swizzle is identity
        if (has_mem && kt == 0 && tid < 128) {
            float g = gate ? (1.0f + gate[b * 1024 + h * 128 + tid]) : 1.0f;
            Kl[tid] = (bf16)(32.0f * mvk[h * 128 + tid] * g);
        }
        __syncthreads();

        // S = Q @ K^T for this wave's 16 rows x 64 cols
        f32x4 accs[4];
#pragma unroll
        for (int tt = 0; tt < 4; ++tt) accs[tt] = zero;
#pragma unroll
        for (int kc = 0; kc < 128; kc += 32) {
            bf16x8 aq = qf[kc >> 5];
#pragma unroll
            for (int tt = 0; tt < 4; ++tt) {
                // swizzled read: chunk = (kc/8 + quad) ^ (row&7), row&7 == l16&7
                bf16x8 bk = *(const bf16x8*)&Kl[(tt * 16 + l16) * 128 +
                                                ((((kc >> 3) + quad) ^ (l16 & 7)) << 3)];
                accs[tt] = __builtin_amdgcn_mfma_f32_16x16x32_bf16(aq, bk, accs[tt], 0, 0, 0);
            }
        }

        // mask + scale (masked_fill BEFORE scale, per reference)
        float sv[4][4];
#pragma unroll
        for (int tt = 0; tt < 4; ++tt) {
            int t = t0 + tt * 16 + l16;
            float mk;
            if (t >= T)        mk = 0.f;
            else if (has_mem)  mk = (t == 0) ? 1.f : mask[b * T0 + t - 1];
            else               mk = mask[b * T0 + t];
#pragma unroll
            for (int r = 0; r < 4; ++r) {
                float x = accs[tt][r];
                x = (mk != 0.f) ? x : -1e9f;
                sv[tt][r] = x * inv_sqrt;
            }
        }

        // online softmax per row (row = quad*4 + r, 16 lanes per row)
#pragma unroll
        for (int r = 0; r < 4; ++r) {
            float mx = fmaxf(fmaxf(sv[0][r], sv[1][r]), fmaxf(sv[2][r], sv[3][r]));
#pragma unroll
            for (int off = 1; off < 16; off <<= 1)
                mx = fmaxf(mx, __shfl_xor(mx, off, 64));
            float m_new = fmaxf(m_st[r], mx);
            float alpha = __expf(m_st[r] - m_new);
            float rsum = 0.f;
#pragma unroll
            for (int tt = 0; tt < 4; ++tt) {
                float p = __expf(sv[tt][r] - m_new);
                sv[tt][r] = p;
                rsum += p;
            }
#pragma unroll
            for (int off = 1; off < 16; off <<= 1)
                rsum += __shfl_xor(rsum, off, 64);
            l_st[r] = l_st[r] * alpha + rsum;
            m_st[r] = m_new;
#pragma unroll
            for (int n = 0; n < 8; ++n) o_acc[n][r] *= alpha;
        }

        // P (C-layout) -> LDS -> A-layout for PV
#pragma unroll
        for (int tt = 0; tt < 4; ++tt)
#pragma unroll
            for (int r = 0; r < 4; ++r)
                Pl[w * 1152 + (quad * 4 + r) * 72 + tt * 16 + l16] = (bf16)sv[tt][r];
        __asm__ volatile("s_waitcnt lgkmcnt(0)" ::: "memory");

#pragma unroll
        for (int kc = 0; kc < 64; kc += 32) {
            bf16x8 ap = *(const bf16x8*)&Pl[w * 1152 + l16 * 72 + kc + quad * 8];
#pragma unroll
            for (int n = 0; n < 8; ++n) {
                int d = n * 16 + l16;
                int ct = ((kc >> 3) + quad) ^ ((d >> 3) & 7);
                bf16x8 bv = *(const bf16x8*)&Vt[d * 72 + (ct << 3)];
                o_acc[n] = __builtin_amdgcn_mfma_f32_16x16x32_bf16(ap, bv, o_acc[n], 0, 0, 0);
            }
        }
    }

    // epilogue: upd = X + O/l  (residual fused), bf16 out
#pragma unroll
    for (int n = 0; n < 8; ++n) {
#pragma unroll
        for (int r = 0; r < 4; ++r) {
            int s = s0 + w * 16 + quad * 4 + r;
            int d = n * 16 + l16;
            size_t off = (size_t)(b * S + s) * 1024 + h * 128 + d;
            float val = o_acc[n][r] / l_st[r];
            upd[off] = (bf16)(X[off] + val);
        }
    }
}

// ---------------------------------------------------------------------------
// Launch
// ---------------------------------------------------------------------------
extern "C" void kernel_launch(void* const* d_in, const int* in_sizes, int n_in,
                              void* d_out, int out_size, void* d_ws, size_t ws_size,
                              hipStream_t stream) {
    (void)in_sizes; (void)n_in; (void)out_size; (void)ws_size;
    const float* v      = (const float*)d_in[0];
    const float* q      = (const float*)d_in[1];
    const float* c      = (const float*)d_in[2];
    const float* v_mask = (const float*)d_in[3];
    const float* q_mask = (const float*)d_in[4];
    const float* c_mask = (const float*)d_in[5];
    const float* Wv4q = (const float*)d_in[6];
    const float* bv4q = (const float*)d_in[7];
    const float* Wq4v = (const float*)d_in[8];
    const float* bq4v = (const float*)d_in[9];
    const float* Wv   = (const float*)d_in[10];
    const float* bv   = (const float*)d_in[11];
    const float* Wq   = (const float*)d_in[12];
    const float* bq   = (const float*)d_in[13];
    const float* Wc   = (const float*)d_in[14];
    const float* bc   = (const float*)d_in[15];
    const float* mvk  = (const float*)d_in[16];
    const float* mvv  = (const float*)d_in[17];
    const float* mck  = (const float*)d_in[18];
    const float* mcv  = (const float*)d_in[19];
    const float* Wvo  = (const float*)d_in[20];
    const float* bvo  = (const float*)d_in[21];
    const float* Wqo  = (const float*)d_in[22];
    const float* bqo  = (const float*)d_in[23];
    const float* Wco  = (const float*)d_in[24];
    const float* bco  = (const float*)d_in[25];
    float* out = (float*)d_out;

    // workspace layout (relu buffers aliased with upd buffers: disjoint lifetimes)
    char* ws = (char*)d_ws;
    size_t o = 0;
    bf16*  reluV  = (bf16*)(ws + o); o += (size_t)16384 * 1024 * 2;
    bf16*  reluQ  = (bf16*)(ws + o); o += (size_t)8192  * 1024 * 2;
    bf16*  reluC  = (bf16*)(ws + o); o += (size_t)16384 * 1024 * 2;
    bf16*  WtV    = (bf16*)(ws + o); o += (size_t)3072 * 1024 * 2;
    bf16*  WtQ    = (bf16*)(ws + o); o += (size_t)3072 * 1024 * 2;
    bf16*  WtC    = (bf16*)(ws + o); o += (size_t)3072 * 1024 * 2;
    bf16*  WtVO   = (bf16*)(ws + o); o += (size_t)1024 * 1024 * 2;
    bf16*  WtQO   = (bf16*)(ws + o); o += (size_t)1024 * 1024 * 2;
    bf16*  WtCO   = (bf16*)(ws + o); o += (size_t)1024 * 1024 * 2;
    bf16*  transV = (bf16*)(ws + o); o += (size_t)16384 * 3072 * 2;
    bf16*  transQ = (bf16*)(ws + o); o += (size_t)8192  * 3072 * 2;
    bf16*  transC = (bf16*)(ws + o); o += (size_t)16384 * 3072 * 2;
    float* meanV  = (float*)(ws + o); o += (size_t)32 * 1024 * 4;
    float* meanQ  = (float*)(ws + o); o += (size_t)32 * 1024 * 4;
    float* gV4Q   = (float*)(ws + o); o += (size_t)32 * 1024 * 4;   // from v_mean, applied to q
    float* gQ4V   = (float*)(ws + o); o += (size_t)32 * 1024 * 4;   // from q_mean, applied to v
    bf16* updV = reluV;   // alias: relu dead after QKV GEMMs
    bf16* updQ = reluQ;
    bf16* updC = reluC;

    // 1) relu + cast to bf16 (feeds QKV GEMM A operand)
    relu_cast_kernel<<<8192, 256, 0, stream>>>(v, reluV, 2097152);
    relu_cast_kernel<<<4096, 256, 0, stream>>>(q, reluQ, 1048576);
    relu_cast_kernel<<<8192, 256, 0, stream>>>(c, reluC, 2097152);

    // 2) masked means (fp32)
    mean_kernel<<<dim3(4, 32), 256, 0, stream>>>(v, v_mask, meanV, 512);
    mean_kernel<<<dim3(4, 32), 256, 0, stream>>>(q, q_mask, meanQ, 256);

    // 3) gates: v4q = sigmoid(relu(v_mean)@Wv4q + b), q4v = sigmoid(relu(q_mean)@Wq4v + b)
    gate_kernel<<<dim3(4, 32), 256, 0, stream>>>(meanV, Wv4q, bv4q, gV4Q);
    gate_kernel<<<dim3(4, 32), 256, 0, stream>>>(meanQ, Wq4v, bq4v, gQ4V);

    // 4) weight transposes (fp32 -> bf16) for GEMM B^T layout
    transpose_kernel<<<dim3(32, 96), dim3(32, 8), 0, stream>>>(Wv,  WtV,  1024, 3072);
    transpose_kernel<<<dim3(32, 96), dim3(32, 8), 0, stream>>>(Wq,  WtQ,  1024, 3072);
    transpose_kernel<<<dim3(32, 96), dim3(32, 8), 0, stream>>>(Wc,  WtC,  1024, 3072);
    transpose_kernel<<<dim3(32, 32), dim3(32, 8), 0, stream>>>(Wvo, WtVO, 1024, 1024);
    transpose_kernel<<<dim3(32, 32), dim3(32, 8), 0, stream>>>(Wqo, WtQO, 1024, 1024);
    transpose_kernel<<<dim3(32, 32), dim3(32, 8), 0, stream>>>(Wco, WtCO, 1024, 1024);

    // 5) QKV projections: trans = (relu(x)@W + b)*mask, k/q thirds *(1+gate)
    gemm_bt<bf16><<<dim3(24, 128), 256, 0, stream>>>(reluV, WtV, bv, transV, 16384, 3072, v_mask, gQ4V, 9);
    gemm_bt<bf16><<<dim3(24, 64),  256, 0, stream>>>(reluQ, WtQ, bq, transQ, 8192,  3072, q_mask, gV4Q, 8);
    gemm_bt<bf16><<<dim3(24, 128), 256, 0, stream>>>(reluC, WtC, bc, transC, 16384, 3072, c_mask, nullptr, 9);

    // 6) fused attention (+ residual): upd = x + attn(...)
    attn_kernel<<<dim3(8, 8, 32), 256, 0, stream>>>(transV, v, updV, v_mask, gQ4V, mvk, mvv, 512, 512, 1);
    attn_kernel<<<dim3(4, 8, 32), 256, 0, stream>>>(transQ, q, updQ, q_mask, nullptr, nullptr, nullptr, 256, 256, 0);
    attn_kernel<<<dim3(8, 8, 32), 256, 0, stream>>>(transC, c, updC, c_mask, nullptr, mck, mcv, 512, 512, 1);

    // 7) output projections -> d_out fp32 (concatenated v, q, c)
    gemm_bt<float><<<dim3(8, 128), 256, 0, stream>>>(updV, WtVO, bvo, out,            16384, 1024, nullptr, nullptr, 0);
    gemm_bt<float><<<dim3(8, 64),  256, 0, stream>>>(updQ, WtQO, bqo, out + 16777216, 8192,  1024, nullptr, nullptr, 0);
    gemm_bt<float><<<dim3(8, 128), 256, 0, stream>>>(updC, WtCO, bco, out + 25165824, 16384, 1024, nullptr, nullptr, 0);
}

// Round 2
// 1635.220 us; speedup vs baseline: 1.2078x; 1.0132x over previous
//
#include <hip/hip_runtime.h>
#include <hip/hip_bf16.h>

// ---------------------------------------------------------------------------
// Types
// ---------------------------------------------------------------------------
typedef __bf16 bf16;
typedef __bf16 bf16x8 __attribute__((ext_vector_type(8)));
typedef float  f32x4  __attribute__((ext_vector_type(4)));

// async global->LDS, 16B per lane; LDS dest = wave-uniform base + lane*16
__device__ __forceinline__ void gl2lds16(const bf16* g, bf16* l) {
    __builtin_amdgcn_global_load_lds((const __attribute__((address_space(1))) void*)g,
                                     (__attribute__((address_space(3))) void*)l,
                                     16, 0, 0);
}

// counted-vmcnt + raw barrier (publishes each wave's covered gl2lds writes)
__device__ __forceinline__ void vm_bar4() {
    asm volatile("s_waitcnt vmcnt(4)" ::: "memory");
    __builtin_amdgcn_s_barrier();
    asm volatile("" ::: "memory");
}
__device__ __forceinline__ void vm_bar0() {
    asm volatile("s_waitcnt vmcnt(0)" ::: "memory");
    __builtin_amdgcn_s_barrier();
    asm volatile("" ::: "memory");
}

// ---------------------------------------------------------------------------
// relu + cast: fp32 in, bf16 out. 8 elems / thread.
// ---------------------------------------------------------------------------
__global__ void relu_cast_kernel(const float* __restrict__ x, bf16* __restrict__ y, int n8) {
    int i = blockIdx.x * 256 + threadIdx.x;
    if (i >= n8) return;
    const float4* xp = (const float4*)x + (size_t)i * 2;
    float4 a = xp[0], b = xp[1];
    bf16x8 o;
    o[0] = (bf16)fmaxf(a.x, 0.f); o[1] = (bf16)fmaxf(a.y, 0.f);
    o[2] = (bf16)fmaxf(a.z, 0.f); o[3] = (bf16)fmaxf(a.w, 0.f);
    o[4] = (bf16)fmaxf(b.x, 0.f); o[5] = (bf16)fmaxf(b.y, 0.f);
    o[6] = (bf16)fmaxf(b.z, 0.f); o[7] = (bf16)fmaxf(b.w, 0.f);
    *(bf16x8*)(y + (size_t)i * 8) = o;
}

// ---------------------------------------------------------------------------
// Masked mean: mean[b,n] = sum_s mask[b,s]*x[b,s,n] / sum_s mask[b,s]
// ---------------------------------------------------------------------------
__global__ void mean_kernel(const float* __restrict__ x, const float* __restrict__ mask,
                            float* __restrict__ mean, int S) {
    int b = blockIdx.y;
    int n = blockIdx.x * 256 + threadIdx.x;
    const float* xb = x + (size_t)b * S * 1024;
    const float* mb = mask + (size_t)b * S;
    float acc = 0.f, msum = 0.f;
    for (int s = 0; s < S; ++s) {
        float mk = mb[s];
        msum += mk;
        acc += mk * xb[(size_t)s * 1024 + n];
    }
    mean[b * 1024 + n] = acc / msum;
}

// ---------------------------------------------------------------------------
// gate[b,n] = sigmoid( relu(mean[b,:]) @ W[:,n] + bias[n] )
// ---------------------------------------------------------------------------
__global__ void gate_kernel(const float* __restrict__ mean, const float* __restrict__ W,
                            const float* __restrict__ bias, float* __restrict__ gate) {
    int b = blockIdx.y;
    int n = blockIdx.x * 256 + threadIdx.x;
    const float* mb = mean + b * 1024;
    float acc = 0.f;
    for (int k = 0; k < 1024; ++k) {
        float a = mb[k];
        a = a > 0.f ? a : 0.f;
        acc += a * W[(size_t)k * 1024 + n];
    }
    acc += bias[n];
    gate[b * 1024 + n] = 1.0f / (1.0f + __expf(-acc));
}

// ---------------------------------------------------------------------------
// Wt[n,k] = (bf16)W[k,n]
// ---------------------------------------------------------------------------
__global__ void transpose_kernel(const float* __restrict__ W, bf16* __restrict__ Wt,
                                 int K, int N) {
    __shared__ bf16 tile[32][33];
    int k0 = blockIdx.x * 32, n0 = blockIdx.y * 32;
    int tx = threadIdx.x, ty = threadIdx.y;
#pragma unroll
    for (int i = 0; i < 4; ++i)
        tile[ty * 4 + i][tx] = (bf16)W[(size_t)(k0 + ty * 4 + i) * N + n0 + tx];
    __syncthreads();
#pragma unroll
    for (int i = 0; i < 4; ++i)
        Wt[(size_t)(n0 + ty * 4 + i) * K + k0 + tx] = tile[tx][ty * 4 + i];
}

// ---------------------------------------------------------------------------
// gemm256: C[M,N] = A[M,1024] @ Bt[N,1024]^T (+bias, optional mask/gate)
// 256x256 tile, K fixed 1024 (16 K-tiles of BK=64, each split in 2 kk-groups
// of 32). 8 waves (2Mx4N), 512 threads; wave tile 128x64 = 8x4 f32x4 acc.
// Deep pipeline: per sub-phase {STAGE next tile's kk-group (4x gl2lds) ->
// ds_read frags -> setprio(1) 32 MFMA setprio(0) -> vmcnt(4) -> s_barrier}.
// vmcnt(4) keeps this sub-phase's 4 loads in flight across the barrier; the
// 4 oldest (= exactly the kk-group the next sub-phase reads) are guaranteed
// landed (own-wave vmcnt + barrier publishes cross-wave writes).
// LDS [2buf][A,B][2kk][256*32] bf16 = 128 KiB, rows 32-wide (64 B).
// Swizzle (T2): physical chunk = logical chunk ^ ((row>>1)&3), applied on the
// pre-swizzled GLOBAL source (gl2lds dest stays linear) and on ds_read addr
// => 64 lanes spread 8/group over all 8 four-bank groups (conflict-free).
// ---------------------------------------------------------------------------
template <typename OutT>
__global__ __launch_bounds__(512, 2)
void gemm256(const bf16* __restrict__ A, const bf16* __restrict__ Bt,
             const float* __restrict__ bias, OutT* __restrict__ C,
             int N,
             const float* __restrict__ mask,   // [M] or null
             const float* __restrict__ gate,   // [B,1024] or null
             int s_shift)                      // batch = m >> s_shift
{
    constexpr int KD = 1024;
    constexpr int NT = 16;   // K-tiles of 64
    __shared__ __align__(16) bf16 Ls[2][2][2][8192];  // [buf][A/B][kk][256*32]

    const int tid  = threadIdx.x;
    const int lane = tid & 63, w = tid >> 6;
    const int wm = w >> 2, wn = w & 3;
    const int quad = lane >> 4, l16 = lane & 15;
    const int bn = blockIdx.x, bm = blockIdx.y;

    const bf16* Ab = A  + (size_t)bm * 256 * KD;
    const bf16* Bb = Bt + (size_t)bn * 256 * KD;

    // staging: thread -> (row = tid>>2 in 0..127, chunk = tid&3); issue 2 adds
    // 128 rows. LDS dest linear (elem offset tid*8); global col pre-swizzled.
    const int srow   = tid >> 2;
    const int schunk = tid & 3;
    const int scol   = ((schunk ^ ((srow >> 1) & 3)) << 3);
    const bf16* gA0 = Ab + (size_t)srow * KD + scol;
    const bf16* gB0 = Bb + (size_t)srow * KD + scol;
    const int ldst = w * 512;   // wave-uniform LDS dest (elems); HW adds lane*16B

    // ds_read addressing: row = base + l16, chunk = quad ^ ((l16>>1)&3)
    const int cswz = ((quad ^ ((l16 >> 1) & 3)) << 3);
    const int aoff = (wm * 128 + l16) * 32 + cswz;
    const int boff = (wn * 64  + l16) * 32 + cswz;

    f32x4 acc[8][4];
    f32x4 zero = {0.f, 0.f, 0.f, 0.f};
#pragma unroll
    for (int i = 0; i < 8; ++i)
#pragma unroll
        for (int j = 0; j < 4; ++j) acc[i][j] = zero;

    auto STAGE = [&](int buf, int kk, int t) {
        const bf16* ga = gA0 + t * 64 + kk * 32;
        const bf16* gb = gB0 + t * 64 + kk * 32;
        bf16* la = &Ls[buf][0][kk][ldst];
        bf16* lb = &Ls[buf][1][kk][ldst];
        gl2lds16(ga,              la);
        gl2lds16(ga + 128 * KD,   la + 4096);
        gl2lds16(gb,              lb);
        gl2lds16(gb + 128 * KD,   lb + 4096);
    };

    auto COMPUTE = [&](int buf, int kk) {
        const bf16* Ak = &Ls[buf][0][kk][0];
        const bf16* Bk = &Ls[buf][1][kk][0];
        bf16x8 af[8], bv[4];
#pragma unroll
        for (int mf = 0; mf < 8; ++mf)
            af[mf] = *(const bf16x8*)&Ak[aoff + mf * 512];
#pragma unroll
        for (int nf = 0; nf < 4; ++nf)
            bv[nf] = *(const bf16x8*)&Bk[boff + nf * 512];
        __builtin_amdgcn_s_setprio(1);
#pragma unroll
        for (int mf = 0; mf < 8; ++mf)
#pragma unroll
            for (int nf = 0; nf < 4; ++nf)
                acc[mf][nf] = __builtin_amdgcn_mfma_f32_16x16x32_bf16(
                    af[mf], bv[nf], acc[mf][nf], 0, 0, 0);
        __builtin_amdgcn_s_setprio(0);
    };

    // prologue: stage both kk-groups of tile 0; wait first group only
    STAGE(0, 0, 0);
    STAGE(0, 1, 0);
    vm_bar4();          // kk0(0) landed; kk1(0) still in flight

    int buf = 0;
    for (int t = 0; t < NT - 1; ++t) {
        STAGE(buf ^ 1, 0, t + 1);
        COMPUTE(buf, 0);
        vm_bar4();      // kk1(t) landed; kk0(t+1) in flight
        STAGE(buf ^ 1, 1, t + 1);
        COMPUTE(buf, 1);
        vm_bar4();      // kk0(t+1) landed; kk1(t+1) in flight
        buf ^= 1;
    }
    // peeled last tile (no staging -> must drain for kk1)
    COMPUTE(buf, 0);
    vm_bar0();          // kk1(NT-1) landed
    COMPUTE(buf, 1);

    // epilogue: C/D layout col = lane&15, row = quad*4 + reg
#pragma unroll
    for (int mf = 0; mf < 8; ++mf) {
        int mrow0 = bm * 256 + wm * 128 + mf * 16 + quad * 4;
#pragma unroll
        for (int nf = 0; nf < 4; ++nf) {
            int ncol = bn * 256 + wn * 64 + nf * 16 + l16;
            float bs = bias[ncol];
#pragma unroll
            for (int r = 0; r < 4; ++r) {
                int mr = mrow0 + r;
                float vv = acc[mf][nf][r] + bs;
                if (mask) {
                    vv *= mask[mr];
                    if (gate && ncol < 2048) {
                        int bb = mr >> s_shift;
                        vv *= 1.0f + gate[bb * 1024 + (ncol & 1023)];
                    }
                }
                C[(size_t)mr * N + ncol] = (OutT)vv;
            }
        }
    }
}

// ---------------------------------------------------------------------------
// Fused flash attention over one (b, h, 64-row Q tile).  (unchanged from v2)
// ---------------------------------------------------------------------------
__global__ __launch_bounds__(256)
void attn_kernel(const bf16* __restrict__ trans, const float* __restrict__ X,
                 bf16* __restrict__ upd, const float* __restrict__ mask,
                 const float* __restrict__ gate,   // null => no mem-token gating
                 const float* __restrict__ mvk, const float* __restrict__ mvv,
                 int S, int T0, int has_mem)
{
    const int T = T0 + has_mem;
    const size_t rs = 3072;
    __shared__ __align__(16) bf16 Kl[64 * 128];
    __shared__ __align__(16) bf16 Vt[128 * 72];   // [d][t], stride 72, chunk-swizzled
    __shared__ __align__(16) bf16 Pl[4 * 16 * 72];

    int tid  = threadIdx.x;
    int lane = tid & 63, w = tid >> 6;
    int quad = lane >> 4, l16 = lane & 15;
    int st = blockIdx.x, h = blockIdx.y, b = blockIdx.z;
    int s0 = st * 64;
    const bf16* Tb = trans + (size_t)b * S * rs;   // S == T0 for all modalities

    // Q fragments in registers
    bf16x8 qf[4];
    {
        const bf16* qp = Tb + (size_t)(s0 + w * 16 + l16) * rs + 1024 + h * 128 + quad * 8;
#pragma unroll
        for (int kk = 0; kk < 4; ++kk)
            qf[kk] = *(const bf16x8*)(qp + kk * 32);
    }

    float m_st[4], l_st[4];
    f32x4 o_acc[8];
    f32x4 zero = {0.f, 0.f, 0.f, 0.f};
#pragma unroll
    for (int r = 0; r < 4; ++r) { m_st[r] = -3.0e38f; l_st[r] = 0.f; }
#pragma unroll
    for (int n = 0; n < 8; ++n) o_acc[n] = zero;

    const float inv_sqrt = 0.08838834764831845f;   // 1/sqrt(128)
    int nT = (T + 63) >> 6;
    for (int kt = 0; kt < nT; ++kt) {
        int t0 = kt * 64;
        __syncthreads();   // previous tile's LDS fully consumed

        // stage K tile; LDS dest linear, global source chunk pre-swizzled
#pragma unroll
        for (int p = 0; p < 4; ++p) {
            int c = p * 256 + tid;
            int row = c >> 4;
            int c16 = ((c & 15) ^ (row & 7)) * 8;
            int t = t0 + row;
            int sr = has_mem ? (t - 1) : t;
            sr = sr < 0 ? 0 : sr;
            sr = sr > T0 - 1 ? T0 - 1 : sr;
            gl2lds16(Tb + (size_t)sr * rs + h * 128 + c16,
                     Kl + (size_t)(p * 256 + w * 64) * 8);
        }
        // stage V tile transposed into Vt[d][t], t-chunk swizzled by (d>>3)&7
#pragma unroll
        for (int i = 0; i < 4; ++i) {
            int chunk = i * 256 + tid;
            int tl = chunk >> 4;
            int d8 = (chunk & 15) * 8;
            int t = t0 + tl;
            bf16 vbuf[8];
            if (has_mem && t == 0) {
                const float* mp = mvv + h * 128 + d8;      // mem V (scale 1), fp32
#pragma unroll
                for (int j = 0; j < 8; ++j) vbuf[j] = (bf16)mp[j];
            } else {
                int sr = has_mem ? (t - 1) : t;
                sr = sr < 0 ? 0 : sr;
                sr = sr > T0 - 1 ? T0 - 1 : sr;
                bf16x8 vv = *(const bf16x8*)(Tb + (size_t)sr * rs + 2048 + h * 128 + d8);
#pragma unroll
                for (int j = 0; j < 8; ++j) vbuf[j] = vv[j];
            }
            int tswz = (((tl >> 3) ^ ((d8 >> 3) & 7)) << 3) + (tl & 7);
#pragma unroll
            for (int j = 0; j < 8; ++j)
                Vt[(d8 + j) * 72 + tswz] = vbuf[j];
        }
        __syncthreads();   // drains vmcnt (global_load_lds) + lgkm (ds writes)

        // overwrite mem-token K row: 32 * mvk * (1+gate); row 0 => swizzle identity
        if (has_mem && kt == 0 && tid < 128) {
            float g = gate ? (1.0f + gate[b * 1024 + h * 128 + tid]) : 1.0f;
            Kl[tid] = (bf16)(32.0f * mvk[h * 128 + tid] * g);
        }
        __syncthreads();

        // S = Q @ K^T for this wave's 16 rows x 64 cols
        f32x4 accs[4];
#pragma unroll
        for (int tt = 0; tt < 4; ++tt) accs[tt] = zero;
#pragma unroll
        for (int kc = 0; kc < 128; kc += 32) {
            bf16x8 aq = qf[kc >> 5];
#pragma unroll
            for (int tt = 0; tt < 4; ++tt) {
                bf16x8 bk = *(const bf16x8*)&Kl[(tt * 16 + l16) * 128 +
                                                ((((kc >> 3) + quad) ^ (l16 & 7)) << 3)];
                accs[tt] = __builtin_amdgcn_mfma_f32_16x16x32_bf16(aq, bk, accs[tt], 0, 0, 0);
            }
        }

        // mask + scale (masked_fill BEFORE scale, per reference)
        float sv[4][4];
#pragma unroll
        for (int tt = 0; tt < 4; ++tt) {
            int t = t0 + tt * 16 + l16;
            float mk;
            if (t >= T)        mk = 0.f;
            else if (has_mem)  mk = (t == 0) ? 1.f : mask[b * T0 + t - 1];
            else               mk = mask[b * T0 + t];
#pragma unroll
            for (int r = 0; r < 4; ++r) {
                float x = accs[tt][r];
                x = (mk != 0.f) ? x : -1e9f;
                sv[tt][r] = x * inv_sqrt;
            }
        }

        // online softmax per row (row = quad*4 + r, 16 lanes per row)
#pragma unroll
        for (int r = 0; r < 4; ++r) {
            float mx = fmaxf(fmaxf(sv[0][r], sv[1][r]), fmaxf(sv[2][r], sv[3][r]));
#pragma unroll
            for (int off = 1; off < 16; off <<= 1)
                mx = fmaxf(mx, __shfl_xor(mx, off, 64));
            float m_new = fmaxf(m_st[r], mx);
            float alpha = __expf(m_st[r] - m_new);
            float rsum = 0.f;
#pragma unroll
            for (int tt = 0; tt < 4; ++tt) {
                float p = __expf(sv[tt][r] - m_new);
                sv[tt][r] = p;
                rsum += p;
            }
#pragma unroll
            for (int off = 1; off < 16; off <<= 1)
                rsum += __shfl_xor(rsum, off, 64);
            l_st[r] = l_st[r] * alpha + rsum;
            m_st[r] = m_new;
#pragma unroll
            for (int n = 0; n < 8; ++n) o_acc[n][r] *= alpha;
        }

        // P (C-layout) -> LDS -> A-layout for PV
#pragma unroll
        for (int tt = 0; tt < 4; ++tt)
#pragma unroll
            for (int r = 0; r < 4; ++r)
                Pl[w * 1152 + (quad * 4 + r) * 72 + tt * 16 + l16] = (bf16)sv[tt][r];
        __asm__ volatile("s_waitcnt lgkmcnt(0)" ::: "memory");

#pragma unroll
        for (int kc = 0; kc < 64; kc += 32) {
            bf16x8 ap = *(const bf16x8*)&Pl[w * 1152 + l16 * 72 + kc + quad * 8];
#pragma unroll
            for (int n = 0; n < 8; ++n) {
                int d = n * 16 + l16;
                int ct = ((kc >> 3) + quad) ^ ((d >> 3) & 7);
                bf16x8 bvv = *(const bf16x8*)&Vt[d * 72 + (ct << 3)];
                o_acc[n] = __builtin_amdgcn_mfma_f32_16x16x32_bf16(ap, bvv, o_acc[n], 0, 0, 0);
            }
        }
    }

    // epilogue: upd = X + O/l  (residual fused), bf16 out
#pragma unroll
    for (int n = 0; n < 8; ++n) {
#pragma unroll
        for (int r = 0; r < 4; ++r) {
            int s = s0 + w * 16 + quad * 4 + r;
            int d = n * 16 + l16;
            size_t off = (size_t)(b * S + s) * 1024 + h * 128 + d;
            float val = o_acc[n][r] / l_st[r];
            upd[off] = (bf16)(X[off] + val);
        }
    }
}

// ---------------------------------------------------------------------------
// Launch
// ---------------------------------------------------------------------------
extern "C" void kernel_launch(void* const* d_in, const int* in_sizes, int n_in,
                              void* d_out, int out_size, void* d_ws, size_t ws_size,
                              hipStream_t stream) {
    (void)in_sizes; (void)n_in; (void)out_size; (void)ws_size;
    const float* v      = (const float*)d_in[0];
    const float* q      = (const float*)d_in[1];
    const float* c      = (const float*)d_in[2];
    const float* v_mask = (const float*)d_in[3];
    const float* q_mask = (const float*)d_in[4];
    const float* c_mask = (const float*)d_in[5];
    const float* Wv4q = (const float*)d_in[6];
    const float* bv4q = (const float*)d_in[7];
    const float* Wq4v = (const float*)d_in[8];
    const float* bq4v = (const float*)d_in[9];
    const float* Wv   = (const float*)d_in[10];
    const float* bv   = (const float*)d_in[11];
    const float* Wq   = (const float*)d_in[12];
    const float* bq   = (const float*)d_in[13];
    const float* Wc   = (const float*)d_in[14];
    const float* bc   = (const float*)d_in[15];
    const float* mvk  = (const float*)d_in[16];
    const float* mvv  = (const float*)d_in[17];
    const float* mck  = (const float*)d_in[18];
    const float* mcv  = (const float*)d_in[19];
    const float* Wvo  = (const float*)d_in[20];
    const float* bvo  = (const float*)d_in[21];
    const float* Wqo  = (const float*)d_in[22];
    const float* bqo  = (const float*)d_in[23];
    const float* Wco  = (const float*)d_in[24];
    const float* bco  = (const float*)d_in[25];
    float* out = (float*)d_out;

    // workspace layout (relu buffers aliased with upd buffers: disjoint lifetimes)
    char* ws = (char*)d_ws;
    size_t o = 0;
    bf16*  reluV  = (bf16*)(ws + o); o += (size_t)16384 * 1024 * 2;
    bf16*  reluQ  = (bf16*)(ws + o); o += (size_t)8192  * 1024 * 2;
    bf16*  reluC  = (bf16*)(ws + o); o += (size_t)16384 * 1024 * 2;
    bf16*  WtV    = (bf16*)(ws + o); o += (size_t)3072 * 1024 * 2;
    bf16*  WtQ    = (bf16*)(ws + o); o += (size_t)3072 * 1024 * 2;
    bf16*  WtC    = (bf16*)(ws + o); o += (size_t)3072 * 1024 * 2;
    bf16*  WtVO   = (bf16*)(ws + o); o += (size_t)1024 * 1024 * 2;
    bf16*  WtQO   = (bf16*)(ws + o); o += (size_t)1024 * 1024 * 2;
    bf16*  WtCO   = (bf16*)(ws + o); o += (size_t)1024 * 1024 * 2;
    bf16*  transV = (bf16*)(ws + o); o += (size_t)16384 * 3072 * 2;
    bf16*  transQ = (bf16*)(ws + o); o += (size_t)8192  * 3072 * 2;
    bf16*  transC = (bf16*)(ws + o); o += (size_t)16384 * 3072 * 2;
    float* meanV  = (float*)(ws + o); o += (size_t)32 * 1024 * 4;
    float* meanQ  = (float*)(ws + o); o += (size_t)32 * 1024 * 4;
    float* gV4Q   = (float*)(ws + o); o += (size_t)32 * 1024 * 4;   // from v_mean, applied to q
    float* gQ4V   = (float*)(ws + o); o += (size_t)32 * 1024 * 4;   // from q_mean, applied to v
    bf16* updV = reluV;   // alias: relu dead after QKV GEMMs
    bf16* updQ = reluQ;
    bf16* updC = reluC;

    // 1) relu + cast to bf16 (feeds QKV GEMM A operand)
    relu_cast_kernel<<<8192, 256, 0, stream>>>(v, reluV, 2097152);
    relu_cast_kernel<<<4096, 256, 0, stream>>>(q, reluQ, 1048576);
    relu_cast_kernel<<<8192, 256, 0, stream>>>(c, reluC, 2097152);

    // 2) masked means (fp32)
    mean_kernel<<<dim3(4, 32), 256, 0, stream>>>(v, v_mask, meanV, 512);
    mean_kernel<<<dim3(4, 32), 256, 0, stream>>>(q, q_mask, meanQ, 256);

    // 3) gates
    gate_kernel<<<dim3(4, 32), 256, 0, stream>>>(meanV, Wv4q, bv4q, gV4Q);
    gate_kernel<<<dim3(4, 32), 256, 0, stream>>>(meanQ, Wq4v, bq4v, gQ4V);

    // 4) weight transposes (fp32 -> bf16) for GEMM B^T layout
    transpose_kernel<<<dim3(32, 96), dim3(32, 8), 0, stream>>>(Wv,  WtV,  1024, 3072);
    transpose_kernel<<<dim3(32, 96), dim3(32, 8), 0, stream>>>(Wq,  WtQ,  1024, 3072);
    transpose_kernel<<<dim3(32, 96), dim3(32, 8), 0, stream>>>(Wc,  WtC,  1024, 3072);
    transpose_kernel<<<dim3(32, 32), dim3(32, 8), 0, stream>>>(Wvo, WtVO, 1024, 1024);
    transpose_kernel<<<dim3(32, 32), dim3(32, 8), 0, stream>>>(Wqo, WtQO, 1024, 1024);
    transpose_kernel<<<dim3(32, 32), dim3(32, 8), 0, stream>>>(Wco, WtCO, 1024, 1024);

    // 5) QKV projections: trans = (relu(x)@W + b)*mask, k/q thirds *(1+gate)
    gemm256<bf16><<<dim3(12, 64), 512, 0, stream>>>(reluV, WtV, bv, transV, 3072, v_mask, gQ4V, 9);
    gemm256<bf16><<<dim3(12, 32), 512, 0, stream>>>(reluQ, WtQ, bq, transQ, 3072, q_mask, gV4Q, 8);
    gemm256<bf16><<<dim3(12, 64), 512, 0, stream>>>(reluC, WtC, bc, transC, 3072, c_mask, nullptr, 9);

    // 6) fused attention (+ residual): upd = x + attn(...)
    attn_kernel<<<dim3(8, 8, 32), 256, 0, stream>>>(transV, v, updV, v_mask, gQ4V, mvk, mvv, 512, 512, 1);
    attn_kernel<<<dim3(4, 8, 32), 256, 0, stream>>>(transQ, q, updQ, q_mask, nullptr, nullptr, nullptr, 256, 256, 0);
    attn_kernel<<<dim3(8, 8, 32), 256, 0, stream>>>(transC, c, updC, c_mask, nullptr, mck, mcv, 512, 512, 1);

    // 7) output projections -> d_out fp32 (concatenated v, q, c)
    gemm256<float><<<dim3(4, 64), 512, 0, stream>>>(updV, WtVO, bvo, out,            1024, nullptr, nullptr, 0);
    gemm256<float><<<dim3(4, 32), 512, 0, stream>>>(updQ, WtQO, bqo, out + 16777216, 1024, nullptr, nullptr, 0);
    gemm256<float><<<dim3(4, 64), 512, 0, stream>>>(updC, WtCO, bco, out + 25165824, 1024, nullptr, nullptr, 0);
}